// Round 2
// baseline (150.415 us; speedup 1.0000x reference)
//
#include <hip/hip_runtime.h>

// PositionalCharacterLevelWordSparse:
//   rows = B*W = 65536, L = 16 chars/row, D = 512 + 16 = 528 bins/row.
//   out[row, tok[row,c]]       += (tok != 0)
//   out[row, 512 + pos[row,c]] += (tok != 0)
// Strategy: per-block float LDS histograms (8 rows/block), then coalesced
// nontemporal float4 writes. Write-bound: ~138 MB out, ~8 MB in.
//
// vs R1: (a) input loads issued BEFORE LDS zeroing so HBM/L2 latency hides
// under it, (b) float histogram (native ds_add_f32) so the store loop is a
// pure LDS->global copy, (c) nontemporal stores bypass L2 write-allocate
// (output is 138 MB write-once, 4.3x L2).

constexpr int NUM_EMB = 512;
constexpr int MAX_POS = 16;
constexpr int D = NUM_EMB + MAX_POS;   // 528
constexpr int L = 16;
constexpr int ROWS_PER_BLOCK = 8;
constexpr int THREADS = 256;
constexpr int HIST = ROWS_PER_BLOCK * D;   // 4224 floats = 16.9 KB
constexpr int HIST4 = HIST / 4;            // 1056 float4
constexpr int FULL_IT = HIST4 / THREADS;   // 4 full iterations
constexpr int REM = HIST4 - FULL_IT * THREADS;  // 32 remainder float4s

typedef float v4f __attribute__((ext_vector_type(4)));

__global__ __launch_bounds__(THREADS)
void pcls_hist_kernel(const int* __restrict__ tok,
                      const int* __restrict__ pos,
                      float* __restrict__ out) {
    __shared__ float hist[HIST];

    const int tid = threadIdx.x;
    const long long row_base = (long long)blockIdx.x * ROWS_PER_BLOCK;

    // Issue the input loads FIRST: their latency overlaps the LDS zeroing.
    int t = 0, p = 0;
    if (tid < ROWS_PER_BLOCK * L) {
        const long long g = row_base * L + tid;
        t = tok[g];
        p = pos[g];
    }

    // Zero the 8 row-histograms (float4-wide, unrolled).
    v4f* h4 = reinterpret_cast<v4f*>(hist);
    #pragma unroll
    for (int i = 0; i < FULL_IT; ++i)
        h4[tid + i * THREADS] = (v4f)0.0f;
    if (tid < REM)
        h4[tid + FULL_IT * THREADS] = (v4f)0.0f;
    __syncthreads();

    // Scatter: 128 threads each own one (row, char) slot. Mask BOTH adds.
    if (tid < ROWS_PER_BLOCK * L && t != 0) {
        const int r = tid >> 4;            // tid / L
        atomicAdd(&hist[r * D + t], 1.0f);          // ds_add_f32
        atomicAdd(&hist[r * D + NUM_EMB + p], 1.0f);
    }
    __syncthreads();

    // Stream out: 8 rows * 528 floats contiguous per block, nontemporal.
    v4f* out4 = reinterpret_cast<v4f*>(out + row_base * D);
    #pragma unroll
    for (int i = 0; i < FULL_IT; ++i)
        __builtin_nontemporal_store(h4[tid + i * THREADS], &out4[tid + i * THREADS]);
    if (tid < REM)
        __builtin_nontemporal_store(h4[tid + FULL_IT * THREADS],
                                    &out4[tid + FULL_IT * THREADS]);
}

extern "C" void kernel_launch(void* const* d_in, const int* in_sizes, int n_in,
                              void* d_out, int out_size, void* d_ws, size_t ws_size,
                              hipStream_t stream) {
    const int* tok = (const int*)d_in[0];
    const int* pos = (const int*)d_in[1];
    float* out = (float*)d_out;

    const int n_rows = in_sizes[0] / L;              // 65536
    const int grid = n_rows / ROWS_PER_BLOCK;        // 8192 (65536 % 8 == 0)

    pcls_hist_kernel<<<grid, THREADS, 0, stream>>>(tok, pos, out);
}